// Round 1
// 1490.805 us; speedup vs baseline: 1.0439x; 1.0439x over previous
//
#include <hip/hip_runtime.h>
#include <hip/hip_bf16.h>

#define BB 16
#define TT 16
#define CC 128
#define HW 1024             // 32*32
#define PIX (CC*HW)         // 131072
#define STOT ((long)BB*PIX) // 2M

typedef short short8 __attribute__((ext_vector_type(8)));
typedef float f32x4  __attribute__((ext_vector_type(4)));

__device__ __forceinline__ float sigf(float x) { return 1.0f / (1.0f + __expf(-x)); }
__device__ __forceinline__ float tanhf_fast(float x) {
    float ax = fabsf(x);
    float t = __expf(-2.0f * ax);
    float r = (1.0f - t) / (1.0f + t);
    return copysignf(r, x);
}

// ---- packed hi/lo bf16: uint32 = (bf16(x)<<16) | bf16(x - bf16(x)) ----
__device__ __forceinline__ unsigned pack_hl(float x) {
    unsigned u = __float_as_uint(x);
    unsigned hi = (u + 0x7fffu + ((u >> 16) & 1u)) >> 16;
    float r = x - __uint_as_float(hi << 16);
    unsigned v = __float_as_uint(r);
    unsigned lo = (v + 0x7fffu + ((v >> 16) & 1u)) >> 16;
    return (hi << 16) | lo;
}
__device__ __forceinline__ float unpack_hl(unsigned p) {
    return __uint_as_float(p & 0xffff0000u) + __uint_as_float(p << 16);
}
__device__ __forceinline__ unsigned short pack_bf16(float x) {
    unsigned u = __float_as_uint(x);
    return (unsigned short)((u + 0x7fffu + ((u >> 16) & 1u)) >> 16);
}
__device__ __forceinline__ float bf16f(unsigned short s) {
    return __uint_as_float(((unsigned)s) << 16);
}

// B-side split (activations stay packed u32 in LDS)
__device__ __forceinline__ void split_frag(uint4 a, uint4 b, short8& hi, short8& lo) {
    unsigned w[8] = {a.x, a.y, a.z, a.w, b.x, b.y, b.z, b.w};
    union U { unsigned u[4]; short8 s; } h, l;
    #pragma unroll
    for (int j = 0; j < 4; ++j) {
        h.u[j] = (w[2*j] >> 16)      | (w[2*j+1] & 0xffff0000u);
        l.u[j] = (w[2*j] & 0xffffu)  | (w[2*j+1] << 16);
    }
    hi = h.s; lo = l.s;
}

// B LDS tile addr (u32 units): 128 rows x 32 k-words, stride 36, quad rotate (proven R2-R4)
__device__ __forceinline__ int taddr(int row, int kw) {
    return row * 36 + ((((kw >> 2) + (row >> 2)) & 7) << 2) + (kw & 3);
}

// ---- A (weight) tile image: bf16 hi/lo planes, pre-swizzled, DMA-staged ----
// Per 128x32 tile: hi plane 128 rows x 40 shorts (80 B stride, 16B-aligned rows),
// 4 data blocks of 8 shorts rotated by ((ks>>3)+(row>>2))&3, block 4 = pad.
// lo plane at +10240 B. Tile = 20480 B = 5 rounds x (256 thr x 16 B) global_load_lds.
typedef __attribute__((address_space(3))) unsigned lds_u32_t;
typedef __attribute__((address_space(1))) const unsigned gbl_u32_t;
__device__ __forceinline__ void gld16(const void* g, unsigned* l) {
    __builtin_amdgcn_global_load_lds((gbl_u32_t*)g, (lds_u32_t*)l, 16, 0, 0);
}

// ---------------- MFMA GEMM with fused epilogues ----------------
// MODE 1: bf16 store (+ scalar bias[row])        -> outv = ushort*
// MODE 2: LSTM fuse: rows c*4+gate; stv=Cst(f32), outv=Hp_new(packed)
// MODE 3: final fuse: rows c*4+gate(3+pad); stv=mp(packed), outv=Hp_new, Hout opt fp32
// B-source: m0>=m_split -> actB(kofs 0); k0>=k_split -> actB(kofs k_split); else actA.
// BKIND: 0 = actB packed u32, 1 = actB fp32 (pack on fly), 2 = actB bf16 (expand hi, lo==0)
template<int MODE, int BKIND>
__global__ __launch_bounds__(256, 2) void gemm_mfma(
    const unsigned* __restrict__ Wp, const float* __restrict__ bias,
    const unsigned* __restrict__ actA, long sA,
    const void* __restrict__ actBv, long sB,
    int k_split, int m_split,
    void* __restrict__ outv, void* __restrict__ stv, float* __restrict__ Hout,
    int M, int K)
{
    __shared__ __align__(16) unsigned As[5120];       // 20480 B weight tile image
    __shared__ __align__(16) unsigned Bs[128 * 36];

    const int b  = blockIdx.z;
    const int n0 = blockIdx.x * 128;
    const int m0 = blockIdx.y * 128;
    const int t  = threadIdx.x;
    const int lane = t & 63;
    const int w  = t >> 6;
    const int wm = w & 1, wn = w >> 1;
    const int g  = lane >> 4, pl = lane & 15;
    // A-plane 16B-block rotation: (g + row>>2)&3 -> independent of mt/wm
    const int cb = ((g + (pl >> 2)) & 3) << 4;

    f32x4 acc[4][4] = {};

    for (int k0 = 0; k0 < K; k0 += 32) {
        // stage A (weights): DMA the pre-swizzled 20480 B tile image
        {
            const char* gA = (const char*)Wp +
                (size_t)((m0 >> 7) * (K >> 5) + (k0 >> 5)) * 20480;
            #pragma unroll
            for (int r = 0; r < 5; ++r)
                gld16(gA + r * 4096 + t * 16, As + (r * 1024 + t * 4));
        }
        // stage B (activations), register 4x4 transpose -> [pixel][k]
        {
            const int p4 = t & 31, kq = t >> 5;
            const bool useB = (m0 >= m_split) || (k0 >= k_split);
            const int kofs = (m0 >= m_split) ? 0 : k_split;
            uint4 v[4];
            if (BKIND == 1 && useB) {
                const float* src = (const float*)actBv + (long)b * sB;
                #pragma unroll
                for (int i = 0; i < 4; ++i) {
                    int kc = k0 + 4 * kq + i - kofs;
                    float4 f = *(const float4*)(src + (long)kc * HW + n0 + 4 * p4);
                    v[i].x = pack_hl(f.x); v[i].y = pack_hl(f.y);
                    v[i].z = pack_hl(f.z); v[i].w = pack_hl(f.w);
                }
            } else if (BKIND == 2 && useB) {
                const unsigned short* src = (const unsigned short*)actBv + (long)b * sB;
                #pragma unroll
                for (int i = 0; i < 4; ++i) {
                    int kc = k0 + 4 * kq + i - kofs;
                    uint2 u = *(const uint2*)(src + (long)kc * HW + n0 + 4 * p4);
                    v[i].x = u.x << 16;
                    v[i].y = u.x & 0xffff0000u;
                    v[i].z = u.y << 16;
                    v[i].w = u.y & 0xffff0000u;
                }
            } else {
                const unsigned* src = useB ? ((const unsigned*)actBv + (long)b * sB)
                                           : (actA + (long)b * sA);
                #pragma unroll
                for (int i = 0; i < 4; ++i) {
                    int kc = k0 + 4 * kq + i - (useB ? kofs : 0);
                    v[i] = *(const uint4*)(src + (long)kc * HW + n0 + 4 * p4);
                }
            }
            #pragma unroll
            for (int j = 0; j < 4; ++j) {
                uint4 wv;
                wv.x = ((const unsigned*)&v[0])[j];
                wv.y = ((const unsigned*)&v[1])[j];
                wv.z = ((const unsigned*)&v[2])[j];
                wv.w = ((const unsigned*)&v[3])[j];
                *(uint4*)(Bs + taddr(4 * p4 + j, 4 * kq)) = wv;
            }
        }
        __syncthreads();

        short8 ahi[4], alo[4], bhi[4], blo[4];
        #pragma unroll
        for (int mt = 0; mt < 4; ++mt) {
            int row = 64 * wm + 16 * mt + pl;
            const char* pa = (const char*)As + row * 80 + cb;
            ahi[mt] = *(const short8*)pa;
            alo[mt] = *(const short8*)(pa + 10240);
        }
        #pragma unroll
        for (int nt = 0; nt < 4; ++nt) {
            int prow = 64 * wn + 16 * nt + pl;
            uint4 w0 = *(const uint4*)(Bs + taddr(prow, 8 * g));
            uint4 w1 = *(const uint4*)(Bs + taddr(prow, 8 * g + 4));
            split_frag(w0, w1, bhi[nt], blo[nt]);
        }
        // bf16-only B region (BKIND 2): blo==0 -> skip the ahi*blo pass
        const bool skiplo = (BKIND == 2) && ((m0 >= m_split) || (k0 >= k_split));
        if (skiplo) {
            #pragma unroll
            for (int mt = 0; mt < 4; ++mt)
                #pragma unroll
                for (int nt = 0; nt < 4; ++nt) {
                    acc[mt][nt] = __builtin_amdgcn_mfma_f32_16x16x32_bf16(ahi[mt], bhi[nt], acc[mt][nt], 0, 0, 0);
                    acc[mt][nt] = __builtin_amdgcn_mfma_f32_16x16x32_bf16(alo[mt], bhi[nt], acc[mt][nt], 0, 0, 0);
                }
        } else {
            #pragma unroll
            for (int mt = 0; mt < 4; ++mt)
                #pragma unroll
                for (int nt = 0; nt < 4; ++nt) {
                    acc[mt][nt] = __builtin_amdgcn_mfma_f32_16x16x32_bf16(ahi[mt], bhi[nt], acc[mt][nt], 0, 0, 0);
                    acc[mt][nt] = __builtin_amdgcn_mfma_f32_16x16x32_bf16(ahi[mt], blo[nt], acc[mt][nt], 0, 0, 0);
                    acc[mt][nt] = __builtin_amdgcn_mfma_f32_16x16x32_bf16(alo[mt], bhi[nt], acc[mt][nt], 0, 0, 0);
                }
        }
        __syncthreads();
    }

    if (MODE == 1) {
        #pragma unroll
        for (int mt = 0; mt < 4; ++mt)
            #pragma unroll
            for (int r = 0; r < 4; ++r) {
                int row = m0 + 64 * wm + 16 * mt + 4 * g + r;
                float bb = bias[row];
                #pragma unroll
                for (int nt = 0; nt < 4; ++nt) {
                    int col = n0 + 64 * wn + 16 * nt + pl;
                    ((unsigned short*)outv)[((long)b * M + row) * HW + col] =
                        pack_bf16(acc[mt][nt][r] + bb);
                }
            }
    } else {
        // rows interleaved c*4+gate: one thread's f32x4 = all 4 gates of channel c
        const float4* bias4 = (const float4*)bias;
        unsigned* Hp = (unsigned*)outv;
        #pragma unroll
        for (int mt = 0; mt < 4; ++mt) {
            int c = (m0 >> 2) + 16 * wm + 4 * mt + g;
            float4 bb = bias4[c];
            #pragma unroll
            for (int nt = 0; nt < 4; ++nt) {
                int p = n0 + 64 * wn + 16 * nt + pl;
                long idx = (long)b * PIX + (long)c * HW + p;
                float v0 = acc[mt][nt][0] + bb.x;
                float v1 = acc[mt][nt][1] + bb.y;
                float v2 = acc[mt][nt][2] + bb.z;
                float v3 = acc[mt][nt][3] + bb.w;
                if (MODE == 2) {
                    float* Cst = (float*)stv;
                    float cc = Cst[idx] * sigf(v0) + sigf(v1) * tanhf_fast(v2);
                    Cst[idx] = cc;
                    Hp[idx] = pack_hl(sigf(v3) * tanhf_fast(cc));
                } else {
                    unsigned* mp = (unsigned*)stv;
                    float ot = sigf(v0), gt = tanhf_fast(v1), it = sigf(v2);
                    float mo = unpack_hl(mp[idx]);
                    float mn = gt * it + (1.0f - it) * mo;
                    mp[idx] = pack_hl(mn);
                    float hv = ot * mn;
                    Hp[idx] = pack_hl(hv);
                    if (Hout) Hout[idx] = hv;
                }
            }
        }
    }
}

// ---------------- attention: VKM bf16 [16][640][1024] -> ZHZM bf16 [16][256][1024] ----------------
__global__ __launch_bounds__(1024) void attn_kernel(
    const unsigned short* __restrict__ VKM, unsigned short* __restrict__ ZHZM)
{
    __shared__ float qs[32 * 33];
    const int tid = threadIdx.x;
    const int b = blockIdx.x >> 7, c = blockIdx.x & 127;
    const long base  = ((long)b * 640 + c) * HW;
    const long obase = ((long)b * 256 + c) * HW;

    qs[(tid >> 5) * 33 + (tid & 31)] = bf16f(VKM[base + 256l * HW + tid]);
    __syncthreads();

    const int i = tid >> 5, j = tid & 31;
    float qhT = qs[j * 33 + i];
    float vh  = bf16f(VKM[base + tid]);
    float kh  = bf16f(VKM[base + 128l * HW + tid]);
    float km  = bf16f(VKM[base + 384l * HW + tid]);
    float vm  = bf16f(VKM[base + 512l * HW + tid]);

    float sh = kh * qhT, sm = qhT * km;
    float mh = sh, mm = sm;
    #pragma unroll
    for (int o = 16; o > 0; o >>= 1) {
        mh = fmaxf(mh, __shfl_xor(mh, o, 32));
        mm = fmaxf(mm, __shfl_xor(mm, o, 32));
    }
    float eh = __expf(sh - mh), em = __expf(sm - mm);
    float s1 = eh, s2 = em;
    #pragma unroll
    for (int o = 16; o > 0; o >>= 1) {
        s1 += __shfl_xor(s1, o, 32);
        s2 += __shfl_xor(s2, o, 32);
    }
    ZHZM[obase + tid]             = pack_bf16(vh * (eh / s1));
    ZHZM[obase + 128l * HW + tid] = pack_bf16(vm * (em / s2));
}

// ---------------- one-shot setup: build pre-swizzled hi/lo weight tile images ----------------
__device__ __forceinline__ void wimg(unsigned short* img, int Ktiles, int r, int k, float v) {
    int tile = (r >> 7) * Ktiles + (k >> 5);
    int row = r & 127, ks = k & 31;
    unsigned short* p = img + (size_t)tile * 10240;   // 10240 shorts = 20480 B per tile
    int off = row * 40 + ((((ks >> 3) + (row >> 2)) & 3) << 3) + (ks & 7);
    unsigned u = __float_as_uint(v);
    unsigned short hi = (unsigned short)((u + 0x7fffu + ((u >> 16) & 1u)) >> 16);
    float rr = v - __uint_as_float((unsigned)hi << 16);
    unsigned u2 = __float_as_uint(rr);
    unsigned short lo = (unsigned short)((u2 + 0x7fffu + ((u2 >> 16) & 1u)) >> 16);
    p[off] = hi;
    p[off + 5120] = lo;                               // lo plane at +10240 B
}

__global__ __launch_bounds__(256) void setup_all(
    const float* __restrict__ W5, const float* __restrict__ W8, const float* __restrict__ b8,
    unsigned short* __restrict__ Wp5i,
    unsigned short* __restrict__ Wgi, float* __restrict__ bg4,
    unsigned short* __restrict__ Woi, float* __restrict__ bo4)
{
    int idx = blockIdx.x * 256 + threadIdx.x;
    if (idx < 81920) {                       // W5 [640][128] -> Wp5 image (Ktiles=4)
        int r = idx >> 7, k = idx & 127;
        wimg(Wp5i, 4, r, k, W5[idx]);
        return;
    }
    idx -= 81920;
    if (idx < 131072) {                      // Wg: rows c*4+gate, convs 10..13, K=256 (Ktiles=8)
        int rr = idx >> 8, k = idx & 255;
        int c = rr >> 2, gg = rr & 3;
        wimg(Wgi, 8, rr, k, W8[((long)(4 + gg) * 128 + c) * 256 + k]);
        if (k == 0) bg4[rr] = b8[(4 + gg) * 128 + c];
        return;
    }
    idx -= 131072;                           // Wo: 512 rows x 384, conv6 folded (Ktiles=12)
    if (idx >= 512 * 384) return;
    int rr = idx / 384, k = idx - rr * 384;
    int c = rr >> 2, gg = rr & 3;
    float wv = 0.0f;
    if (gg < 3) {
        const float* wr = W8 + ((long)(1 + gg) * 128 + c) * 256;
        if (k < 128) {
            wv = wr[k];
        } else {
            int i = k - 128;
            float s = 0.0f;
            for (int j = 0; j < 128; ++j)
                s += wr[128 + j] * W8[(long)j * 256 + i];   // Wz = W8[0]
            wv = s;
        }
    }
    wimg(Woi, 12, rr, k, wv);
    if (k == 0) {
        float bb = 0.0f;
        if (gg < 3) {
            bb = b8[(1 + gg) * 128 + c];
            const float* wr = W8 + ((long)(1 + gg) * 128 + c) * 256;
            for (int j = 0; j < 128; ++j) bb += wr[128 + j] * b8[j];  // bz = b8[0]
        }
        bo4[rr] = bb;
    }
}

extern "C" void kernel_launch(void* const* d_in, const int* in_sizes, int n_in,
                              void* d_out, int out_size, void* d_ws, size_t ws_size,
                              hipStream_t stream)
{
    const float* x  = (const float*)d_in[0];   // [16][16][128][1024]
    const float* c0 = (const float*)d_in[1];
    const float* W5 = (const float*)d_in[2];   // [640][128]
    const float* b5 = (const float*)d_in[3];   // [640]
    const float* W8 = (const float*)d_in[4];   // [8][128][256]
    const float* b8 = (const float*)d_in[5];   // [8][128]
    float* out = (float*)d_out;

    const long S = STOT;
    unsigned* Ha   = (unsigned*)d_ws;          // S  (intra-step H, packed hl)
    unsigned* Hb   = Ha + S;                   // S  (cross-step H, packed hl)
    unsigned* mp   = Hb + S;                   // S  (memory state, packed hl)
    float*    Cst  = (float*)(mp + S);         // S  fp32
    unsigned short* Wp5i = (unsigned short*)(Cst + S);  // 20 tiles * 10240 shorts
    unsigned short* Wgi  = Wp5i + 20 * 10240;           // 32 tiles
    unsigned short* Woi  = Wgi + 32 * 10240;            // 48 tiles
    float*    bg4  = (float*)(Woi + 48 * 10240);        // 512
    float*    bo4  = bg4 + 512;                         // 512
    unsigned short* VKM  = (unsigned short*)(bo4 + 512);   // 5S bf16
    unsigned short* ZHZM = VKM + 5 * S;                    // 2S bf16

    hipMemsetAsync(Hb, 0, S * sizeof(unsigned), stream);
    hipMemsetAsync(mp, 0, S * sizeof(unsigned), stream);
    hipMemcpyAsync(Cst, c0, S * sizeof(float), hipMemcpyDeviceToDevice, stream);

    setup_all<<<1600, dim3(256), 0, stream>>>(W5, W8, b8, Wp5i, Wgi, bg4, Woi, bo4);

    const int BIG = 1 << 30;
    const dim3 blk(256);
    for (int t = 0; t < TT; ++t) {
        // gates = Wg * [Hb ; x_t], fused LSTM -> Cst, Ha   (M=512, K=256)
        gemm_mfma<2, 1><<<dim3(8, 4, 16), blk, 0, stream>>>(
            (const unsigned*)Wgi, bg4, Hb, (long)PIX, x + (long)t * PIX, (long)TT * PIX,
            128, BIG, Ha, Cst, nullptr, 512, 256);

        // vh,kh,qh (Ha) + km,vm (mp)   (M=640, K=128) -> VKM bf16
        gemm_mfma<1, 0><<<dim3(8, 5, 16), blk, 0, stream>>>(
            (const unsigned*)Wp5i, b5, Ha, (long)PIX, mp, (long)PIX,
            BIG, 384, VKM, nullptr, nullptr, 640, 128);

        attn_kernel<<<2048, dim3(1024), 0, stream>>>(VKM, ZHZM);

        // o,g,i = Wo * [Ha ; ZHZM(bf16)] (conv6 folded), fused final -> mp, Hb (+out)
        gemm_mfma<3, 2><<<dim3(8, 4, 16), blk, 0, stream>>>(
            (const unsigned*)Woi, bo4, Ha, (long)PIX, ZHZM, 2l * PIX,
            128, BIG, Hb, mp, (t == TT - 1) ? out : nullptr, 512, 384);
    }
}